// Round 1
// baseline (1516.475 us; speedup 1.0000x reference)
//
#include <hip/hip_runtime.h>
#include <stdint.h>

// Problem constants (from reference): preds/targets are (8192, 64, 64) f32.
// N rows, C = 64*64 columns, k = N/2.
#define NROWS 8192
#define NCOLS 4096
#define KSEL  4096
#define THREADS 1024

__device__ __forceinline__ uint32_t orderable(uint32_t b) {
    // monotone map float bits -> uint32 (ascending float <=> ascending uint)
    return b ^ ((b & 0x80000000u) ? 0xFFFFFFFFu : 0x80000000u);
}

__global__ __launch_bounds__(THREADS)
void rank_ic_kernel(const float* __restrict__ preds,
                    const float* __restrict__ targets,
                    float* __restrict__ out) {
    const int c = blockIdx.x;
    const int tid = threadIdx.x;

    // 64 KB: composite sort keys. Phase A: 8192 p-keys. Phase B: [0,4096) t-keys,
    // [4096,8192) p-rank per p-position.
    __shared__ uint64_t keyA[NROWS];

    // ---- Phase 1: load column of preds, build 45-bit composite keys ----
    // ascending key order == descending p, ties by ascending row index
    for (int i = tid; i < NROWS; i += THREADS) {
        float p = preds[(size_t)i * NCOLS + c];
        uint32_t u = orderable(__float_as_uint(p));
        keyA[i] = ((uint64_t)(~u) << 13) | (uint32_t)i;
    }
    __syncthreads();

    // ---- Phase 2: bitonic sort 8192 keys ascending ----
    for (int size = 2; size <= NROWS; size <<= 1) {
        for (int stride = size >> 1; stride > 0; stride >>= 1) {
            for (int t = tid; t < NROWS / 2; t += THREADS) {
                int lo = 2 * t - (t & (stride - 1));
                int hi = lo + stride;
                uint64_t a = keyA[lo];
                uint64_t b = keyA[hi];
                bool desc = (lo & size) != 0;
                if ((a > b) != desc) { keyA[lo] = b; keyA[hi] = a; }
            }
            __syncthreads();
        }
    }

    // ---- Phase 3: p-ranks (with argsort-argsort tie rule) + t keys ----
    // position pos in [0,KSEL) of the descending-p order holds the selected set.
    uint64_t tk[KSEL / THREADS];
    uint64_t prv[KSEL / THREADS];
#pragma unroll
    for (int w = 0; w < KSEL / THREADS; ++w) {
        int pos = tid + w * THREADS;
        uint64_t key = keyA[pos];
        uint32_t pu = (uint32_t)(key >> 13);   // ~orderable(p): equality <=> p equality
        int idx = (int)(key & 8191u);
        // tie group [i..j] within the selected K elements (groups are tiny)
        int i = pos, j = pos;
        while (i > 0 && (uint32_t)(keyA[i - 1] >> 13) == pu) --i;
        while (j < KSEL - 1 && (uint32_t)(keyA[j + 1] >> 13) == pu) ++j;
        prv[w] = (uint64_t)((KSEL - 1) - i - j + pos);
        float tv = targets[(size_t)idx * NCOLS + c];
        uint32_t ut = orderable(__float_as_uint(tv));
        tk[w] = ((uint64_t)ut << 13) | (uint32_t)pos;  // t asc, ties by pos asc
    }
    __syncthreads();
#pragma unroll
    for (int w = 0; w < KSEL / THREADS; ++w) {
        int pos = tid + w * THREADS;
        keyA[pos] = tk[w];
        keyA[KSEL + pos] = prv[w];
    }
    __syncthreads();

    // ---- Phase 4: bitonic sort 4096 t-keys ascending ----
    for (int size = 2; size <= KSEL; size <<= 1) {
        for (int stride = size >> 1; stride > 0; stride >>= 1) {
            for (int t = tid; t < KSEL / 2; t += THREADS) {
                int lo = 2 * t - (t & (stride - 1));
                int hi = lo + stride;
                uint64_t a = keyA[lo];
                uint64_t b = keyA[hi];
                bool desc = (lo & size) != 0;
                if ((a > b) != desc) { keyA[lo] = b; keyA[hi] = a; }
            }
            __syncthreads();
        }
    }

    // ---- Phase 5: sum p_r * t_r (exact int64) ----
    long long local = 0;
    for (int r = tid; r < KSEL; r += THREADS) {
        int pos = (int)(keyA[r] & 8191u);               // low 13 bits = pos
        long long pr = (long long)keyA[KSEL + pos];
        local += pr * (long long)r;                      // t_r == r
    }
    __syncthreads();  // all keyA reads done before reuse as accumulator
    if (tid == 0) keyA[0] = 0;
    __syncthreads();
#pragma unroll
    for (int off = 32; off > 0; off >>= 1)
        local += __shfl_down(local, off, 64);
    if ((tid & 63) == 0)
        atomicAdd((unsigned long long*)&keyA[0], (unsigned long long)local);
    __syncthreads();

    if (tid == 0) {
        double S = (double)(long long)keyA[0];
        double mean = (double)(KSEL - 1) * 0.5;
        double cov = S / (double)KSEL - mean * mean;
        double stdprod = (double)KSEL * (double)(KSEL + 1) / 12.0;
        out[c] = (float)(cov / (stdprod + 1e-8));
    }
}

extern "C" void kernel_launch(void* const* d_in, const int* in_sizes, int n_in,
                              void* d_out, int out_size, void* d_ws, size_t ws_size,
                              hipStream_t stream) {
    const float* preds   = (const float*)d_in[0];
    const float* targets = (const float*)d_in[1];
    float* out = (float*)d_out;
    hipLaunchKernelGGL(rank_ic_kernel, dim3(NCOLS), dim3(THREADS), 0, stream,
                       preds, targets, out);
}

// Round 2
// 1236.585 us; speedup vs baseline: 1.2263x; 1.2263x over previous
//
#include <hip/hip_runtime.h>
#include <stdint.h>

// preds/targets: (8192, 64, 64) f32. N=8192 rows, C=4096 cols, k=N/2.
#define NROWS   8192
#define NCOLS   4096
#define KSEL    4096
#define THREADS 1024
#define EPT     8      // elements per thread
#define TGT     8      // target sub-bin size
#define NSUB    2048   // max sub-bins (>= 256 + 8192/TGT = 1280)

__device__ __forceinline__ uint32_t orderable(uint32_t b) {
    // monotone map float bits -> uint32 (ascending float <=> ascending uint)
    return b ^ ((b & 0x80000000u) ? 0xFFFFFFFFu : 0x80000000u);
}

// ---- shared-memory layout (single 63,496 B block, manually aliased) ----
// phase P:  pD   u32[8192] @0       (32KB)   scattered p-keys
//           pIdx u16[8192] @32768   (16KB)   scattered original idx
// phase T:  tD   u32[4096] @0       (16KB)   scattered t-keys   (aliases pD)
//           tPos u16[4096] @16384   ( 8KB)   scattered pos      (aliases pD)
// both:     cnt  u32[2048] @49152   ( 8KB)   sub-bin counters / offsets
//           subBase u16[256] @57344, nsplit u16[256] @57856
//           scanTmp u32[1024] @58368 (4KB)
//           histA u32[256]  @62464  (1KB)
//           sumAcc u64      @63488

__device__ __forceinline__ void alloc_subbins(uint32_t* histA, uint16_t* nsplit,
                                              uint16_t* subBase, uint32_t* scanTmp,
                                              int tid) {
    uint32_t ns = 0;
    if (tid < 256) {
        uint32_t n = histA[tid];
        ns = (n + TGT - 1) / TGT;
        scanTmp[tid] = ns;
    }
    __syncthreads();
    for (int off = 1; off < 256; off <<= 1) {
        uint32_t x = 0, y = 0;
        if (tid < 256) { x = scanTmp[tid]; if (tid >= off) y = scanTmp[tid - off]; }
        __syncthreads();
        if (tid < 256) scanTmp[tid] = x + y;
        __syncthreads();
    }
    if (tid < 256) {
        subBase[tid] = (uint16_t)(scanTmp[tid] - ns);  // exclusive
        nsplit[tid]  = (uint16_t)ns;
    }
    __syncthreads();
}

__device__ __forceinline__ void scan2048_to_offsets(uint32_t* cnt, uint32_t* scanTmp,
                                                    int tid) {
    // exclusive scan of cnt[0..2047] written back in place
    uint32_t a = cnt[2 * tid], b = cnt[2 * tid + 1];
    scanTmp[tid] = a + b;
    __syncthreads();
    for (int off = 1; off < 1024; off <<= 1) {
        uint32_t x = scanTmp[tid];
        uint32_t y = (tid >= off) ? scanTmp[tid - off] : 0u;
        __syncthreads();
        scanTmp[tid] = x + y;
        __syncthreads();
    }
    uint32_t ex = scanTmp[tid] - (a + b);
    cnt[2 * tid] = ex;
    cnt[2 * tid + 1] = ex + a;
    __syncthreads();
}

__global__ __launch_bounds__(THREADS, 8)
void rank_ic_kernel(const float* __restrict__ preds,
                    const float* __restrict__ targets,
                    float* __restrict__ out) {
    const int c = blockIdx.x;
    const int tid = threadIdx.x;

    __shared__ uint64_t smem8[7937];  // 63,496 bytes
    uint8_t*  base    = (uint8_t*)smem8;
    uint32_t* pD      = (uint32_t*)(base);
    uint16_t* pIdx    = (uint16_t*)(base + 32768);
    uint32_t* tD      = (uint32_t*)(base);
    uint16_t* tPos    = (uint16_t*)(base + 16384);
    uint32_t* cnt     = (uint32_t*)(base + 49152);
    uint16_t* subBase = (uint16_t*)(base + 57344);
    uint16_t* nsplit  = (uint16_t*)(base + 57856);
    uint32_t* scanTmp = (uint32_t*)(base + 58368);
    uint32_t* histA   = (uint32_t*)(base + 62464);
    unsigned long long* sumAcc = (unsigned long long*)(base + 63488);

    uint32_t d[EPT];   // p-phase: d = ~orderable(p) (ascending d == descending p)
    uint32_t sb[EPT];  // sub-bin of each owned element
    uint32_t rp[EPT];  // packed: low16 = rank(pos), high16 = p_r

    // ---- load p column, build keys ----
#pragma unroll
    for (int j = 0; j < EPT; ++j) {
        int idx = j * THREADS + tid;
        float p = preds[(size_t)idx * NCOLS + c];
        d[j] = ~orderable(__float_as_uint(p));
    }

    // ---- p: top-8 histogram ----
    cnt[tid] = 0; cnt[tid + 1024] = 0;
    if (tid < 256) histA[tid] = 0;
    __syncthreads();
#pragma unroll
    for (int j = 0; j < EPT; ++j) atomicAdd(&histA[d[j] >> 24], 1u);
    __syncthreads();

    alloc_subbins(histA, nsplit, subBase, scanTmp, tid);

    // ---- p: sub-bin assignment + count ----
#pragma unroll
    for (int j = 0; j < EPT; ++j) {
        uint32_t b = d[j] >> 24;
        uint32_t w = (d[j] >> 16) & 255u;
        uint32_t s = (uint32_t)subBase[b] + ((w * (uint32_t)nsplit[b]) >> 8);
        sb[j] = s;
        atomicAdd(&cnt[s], 1u);
    }
    __syncthreads();

    scan2048_to_offsets(cnt, scanTmp, tid);

    // ---- p: scatter (cnt walks start -> end) ----
#pragma unroll
    for (int j = 0; j < EPT; ++j) {
        uint32_t pos = atomicAdd(&cnt[sb[j]], 1u);
        pD[pos]   = d[j];
        pIdx[pos] = (uint16_t)(j * THREADS + tid);
    }
    __syncthreads();

    // ---- p: rank scan within sub-bin (exact composite rank) ----
#pragma unroll
    for (int j = 0; j < EPT; ++j) {
        uint32_t s = sb[j];
        uint32_t start = s ? cnt[s - 1] : 0u;   // end of previous sub-bin == start
        uint32_t end   = cnt[s];
        uint32_t dl = d[j];
        uint32_t myidx = (uint32_t)(j * THREADS + tid);
        uint32_t less = 0, eqb = 0, eq = 0;
        for (uint32_t q = start; q < end; ++q) {
            uint32_t dv = pD[q];
            less += (dv < dl);
            if (dv == dl) { eq++; eqb += ((uint32_t)pIdx[q] < myidx); }
        }
        uint32_t r = start + less + eqb;        // global rank, ascending d == descending p
        int i  = (int)(start + less);           // first member of tie group
        int jj = i + (int)eq - 1;               // last member (may straddle k boundary)
        if (jj > KSEL - 1) jj = KSEL - 1;
        int pr = (KSEL - 1) - i - jj + (int)r;  // argsort-argsort tie rule (verified R1)
        rp[j] = r | ((uint32_t)(pr & 0xFFFF) << 16);
    }
    __syncthreads();  // pD/pIdx dead after this; region aliased by tD/tPos below

    // ---- t-phase ----
    cnt[tid] = 0; cnt[tid + 1024] = 0;
    if (tid < 256) histA[tid] = 0;
    __syncthreads();
#pragma unroll
    for (int j = 0; j < EPT; ++j) {
        bool act = (rp[j] & 0xFFFFu) < KSEL;
        if (act) {
            float t = targets[(size_t)(j * THREADS + tid) * NCOLS + c];
            d[j] = orderable(__float_as_uint(t));   // ascending t
            atomicAdd(&histA[d[j] >> 24], 1u);
        }
    }
    __syncthreads();

    alloc_subbins(histA, nsplit, subBase, scanTmp, tid);

#pragma unroll
    for (int j = 0; j < EPT; ++j) {
        if ((rp[j] & 0xFFFFu) < KSEL) {
            uint32_t b = d[j] >> 24;
            uint32_t w = (d[j] >> 16) & 255u;
            uint32_t s = (uint32_t)subBase[b] + ((w * (uint32_t)nsplit[b]) >> 8);
            sb[j] = s;
            atomicAdd(&cnt[s], 1u);
        }
    }
    __syncthreads();

    scan2048_to_offsets(cnt, scanTmp, tid);

#pragma unroll
    for (int j = 0; j < EPT; ++j) {
        if ((rp[j] & 0xFFFFu) < KSEL) {
            uint32_t pos = atomicAdd(&cnt[sb[j]], 1u);
            tD[pos]   = d[j];
            tPos[pos] = (uint16_t)(rp[j] & 0xFFFFu);
        }
    }
    __syncthreads();

    long long S = 0;
#pragma unroll
    for (int j = 0; j < EPT; ++j) {
        uint32_t myPos = rp[j] & 0xFFFFu;
        if (myPos < KSEL) {
            uint32_t s = sb[j];
            uint32_t start = s ? cnt[s - 1] : 0u;
            uint32_t end   = cnt[s];
            uint32_t tl = d[j];
            uint32_t less = 0, eqb = 0;
            for (uint32_t q = start; q < end; ++q) {
                uint32_t tv = tD[q];
                less += (tv < tl);
                eqb  += (tv == tl && (uint32_t)tPos[q] < myPos);
            }
            uint32_t tr = start + less + eqb;   // t-rank, ties by pos (verified rule)
            S += (long long)(int)(rp[j] >> 16) * (long long)tr;
        }
    }

    // ---- reduce + epilogue (identical math to round-1 verified kernel) ----
    __syncthreads();
    if (tid == 0) *sumAcc = 0ull;
    __syncthreads();
#pragma unroll
    for (int off = 32; off > 0; off >>= 1)
        S += __shfl_down(S, off, 64);
    if ((tid & 63) == 0)
        atomicAdd(sumAcc, (unsigned long long)S);
    __syncthreads();

    if (tid == 0) {
        double Sd = (double)(long long)(*sumAcc);
        double mean = (double)(KSEL - 1) * 0.5;
        double cov = Sd / (double)KSEL - mean * mean;
        double stdprod = (double)KSEL * (double)(KSEL + 1) / 12.0;
        out[c] = (float)(cov / (stdprod + 1e-8));
    }
}

extern "C" void kernel_launch(void* const* d_in, const int* in_sizes, int n_in,
                              void* d_out, int out_size, void* d_ws, size_t ws_size,
                              hipStream_t stream) {
    const float* preds   = (const float*)d_in[0];
    const float* targets = (const float*)d_in[1];
    float* out = (float*)d_out;
    hipLaunchKernelGGL(rank_ic_kernel, dim3(NCOLS), dim3(THREADS), 0, stream,
                       preds, targets, out);
}

// Round 3
// 823.390 us; speedup vs baseline: 1.8417x; 1.5018x over previous
//
#include <hip/hip_runtime.h>
#include <stdint.h>

// preds/targets: (8192, 64, 64) f32. N=8192 rows, C=4096 cols, k=N/2.
#define NROWS   8192
#define NCOLS   4096
#define KSEL    4096
#define THREADS 1024
#define NSUBP   2560   // max sub-bins: 256 + 8192/TGT = 2304 <= 2560 (p); t needs <=1280
#define TGT     4

// ---- LDS layout (64,600 B total) ----
// p-phase: pD u32[8192]@0 | pIdx u16[8192]@32768 | cnt u32[2560]@49152 |
//          histW u32[4*256]@59392 | combo u32[256]@63488 | wtot u32[16]@64512 |
//          wtot2 u32[4]@64576 | sumAcc u64@64592
// t-phase: tstage u32[8192]@0 (then dead) -> tD u32[4096]@0 | tPos u16[4096]@16384 |
//          prArr u16[4096]@24576 | cnt/histW/combo/wtot same as p.

__device__ __forceinline__ uint32_t orderable(uint32_t b) {
    return b ^ ((b & 0x80000000u) ? 0xFFFFFFFFu : 0x80000000u);
}

__device__ __forceinline__ uint32_t wave_incl_scan(uint32_t v, int lane) {
#pragma unroll
    for (int off = 1; off < 64; off <<= 1) {
        uint32_t n = __shfl_up(v, off, 64);
        if (lane >= off) v += n;
    }
    return v;
}

// histW (4 private copies of 256 bins) -> combo[b] = (subBase<<16)|nsplit
__device__ __forceinline__ void alloc_subbins(uint32_t* histW, uint32_t* combo,
                                              uint32_t* wtot2, int tid, int lane, int wave) {
    uint32_t myNs = 0, myIncl = 0;
    if (tid < 256) {
        uint32_t n = histW[tid] + histW[256 + tid] + histW[512 + tid] + histW[768 + tid];
        myNs = (n + TGT - 1) / TGT;
        myIncl = wave_incl_scan(myNs, lane);
        if (lane == 63) wtot2[wave] = myIncl;
    }
    __syncthreads();
    if (tid < 4) {
        uint32_t orig = wtot2[tid], v = orig;
        uint32_t n1 = __shfl_up(v, 1, 64); if (tid >= 1) v += n1;
        uint32_t n2 = __shfl_up(v, 2, 64); if (tid >= 2) v += n2;
        wtot2[tid] = v - orig;   // exclusive
    }
    __syncthreads();
    if (tid < 256) combo[tid] = ((wtot2[wave] + myIncl - myNs) << 16) | myNs;
    __syncthreads();
}

// exclusive scan of cnt[0..NSUBP) in place (3 barriers)
__device__ __forceinline__ void scan_cnt(uint32_t* cnt, uint32_t* wtot,
                                         int tid, int lane, int wave) {
    uint4 c4 = make_uint4(0, 0, 0, 0);
    bool act = tid < (NSUBP / 4);
    if (act) c4 = ((uint4*)cnt)[tid];
    uint32_t s4 = c4.x + c4.y + c4.z + c4.w;
    uint32_t incl = wave_incl_scan(s4, lane);
    if (lane == 63) wtot[wave] = incl;
    __syncthreads();
    if (tid < 16) {
        uint32_t orig = wtot[tid], v = orig;
#pragma unroll
        for (int off = 1; off < 16; off <<= 1) {
            uint32_t n = __shfl_up(v, off, 64);
            if (tid >= off) v += n;
        }
        wtot[tid] = v - orig;
    }
    __syncthreads();
    if (act) {
        uint32_t base = wtot[wave] + incl - s4;
        uint4 o; o.x = base; o.y = base + c4.x; o.z = o.y + c4.y; o.w = o.z + c4.z;
        ((uint4*)cnt)[tid] = o;
    }
    __syncthreads();
}

__device__ __forceinline__ uint32_t bin_of(uint32_t key, const uint32_t* combo) {
    uint32_t cb = combo[key >> 24];
    return (cb >> 16) + ((((key >> 16) & 255u) * (cb & 0xFFFFu)) >> 8);
}

__global__ __launch_bounds__(THREADS, 8)
void rank_ic_kernel(const float* __restrict__ preds,
                    const float* __restrict__ targets,
                    float* __restrict__ out) {
    const int bid = blockIdx.x;
    // XCD swizzle: concurrent same-XCD blocks get contiguous columns -> L2 line reuse
    const int c = ((bid & 7) << 9) | (bid >> 3);
    const int tid = threadIdx.x;
    const int lane = tid & 63;
    const int wave = tid >> 6;
    const int hg = wave >> 2;  // histogram copy 0..3

    __shared__ __align__(16) uint8_t smem[64600];
    uint32_t* pD     = (uint32_t*)smem;
    uint16_t* pIdx   = (uint16_t*)(smem + 32768);
    uint32_t* cnt    = (uint32_t*)(smem + 49152);
    uint32_t* histW  = (uint32_t*)(smem + 59392);
    uint32_t* combo  = (uint32_t*)(smem + 63488);
    uint32_t* wtot   = (uint32_t*)(smem + 64512);
    uint32_t* wtot2  = (uint32_t*)(smem + 64576);
    unsigned long long* sumAcc = (unsigned long long*)(smem + 64592);
    uint32_t* tstage = (uint32_t*)smem;               // aliases pD (after p-scan)
    uint32_t* tD     = (uint32_t*)smem;
    uint16_t* tPos   = (uint16_t*)(smem + 16384);
    uint16_t* prArr  = (uint16_t*)(smem + 24576);

    // ---- p: load column, build keys (ascending d == descending p) ----
    uint32_t d[8];
#pragma unroll
    for (int j = 0; j < 8; ++j) {
        int row = j * THREADS + tid;
        d[j] = ~orderable(__float_as_uint(preds[(size_t)row * NCOLS + c]));
    }

    // ---- p: privatized top-8 histogram ----
    histW[tid] = 0;
    for (int i = tid; i < NSUBP; i += THREADS) cnt[i] = 0;
    __syncthreads();
#pragma unroll
    for (int j = 0; j < 8; ++j) atomicAdd(&histW[hg * 256 + (d[j] >> 24)], 1u);
    __syncthreads();

    alloc_subbins(histW, combo, wtot2, tid, lane, wave);

    // ---- p: count ----
#pragma unroll
    for (int j = 0; j < 8; ++j) atomicAdd(&cnt[bin_of(d[j], combo)], 1u);
    __syncthreads();

    scan_cnt(cnt, wtot, tid, lane, wave);

    // ---- p: scatter ----
#pragma unroll
    for (int j = 0; j < 8; ++j) {
        uint32_t s = bin_of(d[j], combo);
        uint32_t pos = atomicAdd(&cnt[s], 1u);
        pD[pos]   = d[j];
        pIdx[pos] = (uint16_t)(j * THREADS + tid);
    }
    __syncthreads();

    // ---- p: position-space rank scan (positions tid*8 .. tid*8+7) ----
    uint32_t k8[8], idx8[8], rp[8];  // rp: low16 = rank, high16 = p_r
    {
        uint4 ka = ((const uint4*)pD)[tid * 2];
        uint4 kb = ((const uint4*)pD)[tid * 2 + 1];
        k8[0]=ka.x; k8[1]=ka.y; k8[2]=ka.z; k8[3]=ka.w;
        k8[4]=kb.x; k8[5]=kb.y; k8[6]=kb.z; k8[7]=kb.w;
        uint4 ib = ((const uint4*)pIdx)[tid];
        idx8[0]=ib.x&0xFFFFu; idx8[1]=ib.x>>16; idx8[2]=ib.y&0xFFFFu; idx8[3]=ib.y>>16;
        idx8[4]=ib.z&0xFFFFu; idx8[5]=ib.z>>16; idx8[6]=ib.w&0xFFFFu; idx8[7]=ib.w>>16;
    }
#pragma unroll
    for (int j = 0; j < 8; ++j) {
        uint32_t kl = k8[j];
        uint32_t s = bin_of(kl, combo);
        uint32_t start = s ? cnt[s - 1] : 0u;   // post-scatter: cnt[s-1] == start of s
        uint32_t end   = cnt[s];
        uint32_t a0 = start & ~3u;
        uint32_t less = 0, eq = 0;
        for (uint32_t q = a0; q < end; q += 4) {
            uint4 kv = ((const uint4*)pD)[q >> 2];
            less += (kv.x < kl) + (kv.y < kl) + (kv.z < kl) + (kv.w < kl);
            eq   += (kv.x == kl) + (kv.y == kl) + (kv.z == kl) + (kv.w == kl);
        }
        uint32_t i = a0 + less;                 // first member of tie group
        uint32_t eqb = 0;
        if (eq > 1) {                           // rare: real f32 ties
            uint32_t myidx = idx8[j];
            for (uint32_t q = start; q < end; ++q)
                if (pD[q] == kl) eqb += (pIdx[q] < myidx);
        }
        uint32_t r = i + eqb;
        int jj = (int)(i + eq - 1); if (jj > KSEL - 1) jj = KSEL - 1;
        int pr = (KSEL - 1) - (int)i - jj + (int)r;  // verified tie rule (R1/R2)
        rp[j] = r | ((uint32_t)pr << 16);
    }
    __syncthreads();  // pD/pIdx/cnt reads done

    // ---- t: stage column into LDS by row (keeps global loads in one pattern) ----
#pragma unroll
    for (int j = 0; j < 8; ++j) {
        int row = j * THREADS + tid;
        tstage[row] = orderable(__float_as_uint(targets[(size_t)row * NCOLS + c]));
    }
    __syncthreads();
    uint32_t tk[8];
#pragma unroll
    for (int j = 0; j < 8; ++j) tk[j] = tstage[idx8[j]];
    __syncthreads();  // tstage dead

    // ---- t: zero + prArr + histogram (selected only) ----
    histW[tid] = 0;
    for (int i = tid; i < NSUBP; i += THREADS) cnt[i] = 0;
#pragma unroll
    for (int j = 0; j < 8; ++j)
        if ((rp[j] & 0xFFFFu) < KSEL) prArr[rp[j] & 0xFFFFu] = (uint16_t)(rp[j] >> 16);
    __syncthreads();
#pragma unroll
    for (int j = 0; j < 8; ++j)
        if ((rp[j] & 0xFFFFu) < KSEL) atomicAdd(&histW[hg * 256 + (tk[j] >> 24)], 1u);
    __syncthreads();

    alloc_subbins(histW, combo, wtot2, tid, lane, wave);

#pragma unroll
    for (int j = 0; j < 8; ++j)
        if ((rp[j] & 0xFFFFu) < KSEL) atomicAdd(&cnt[bin_of(tk[j], combo)], 1u);
    __syncthreads();

    scan_cnt(cnt, wtot, tid, lane, wave);

    if (tid == 0) *sumAcc = 0ull;
#pragma unroll
    for (int j = 0; j < 8; ++j) {
        uint32_t r = rp[j] & 0xFFFFu;
        if (r < KSEL) {
            uint32_t s = bin_of(tk[j], combo);
            uint32_t pos = atomicAdd(&cnt[s], 1u);
            tD[pos]   = tk[j];
            tPos[pos] = (uint16_t)r;    // tie-break by p-position
        }
    }
    __syncthreads();

    // ---- t: position-space rank scan + dot product (positions tid*4 ..) ----
    long long S = 0;
    {
        uint4 kv4 = ((const uint4*)tD)[tid];
        uint2 pp  = ((const uint2*)tPos)[tid];
        uint32_t kk[4] = {kv4.x, kv4.y, kv4.z, kv4.w};
        uint32_t pq[4] = {pp.x & 0xFFFFu, pp.x >> 16, pp.y & 0xFFFFu, pp.y >> 16};
#pragma unroll
        for (int m = 0; m < 4; ++m) {
            uint32_t kl = kk[m], mypos = pq[m];
            uint32_t s = bin_of(kl, combo);
            uint32_t start = s ? cnt[s - 1] : 0u;
            uint32_t end   = cnt[s];
            uint32_t a0 = start & ~3u;
            uint32_t less = 0, eq = 0;
            for (uint32_t q = a0; q < end; q += 4) {
                uint4 kv = ((const uint4*)tD)[q >> 2];
                less += (kv.x < kl) + (kv.y < kl) + (kv.z < kl) + (kv.w < kl);
                eq   += (kv.x == kl) + (kv.y == kl) + (kv.z == kl) + (kv.w == kl);
            }
            uint32_t eqb = 0;
            if (eq > 1) {
                for (uint32_t q = start; q < end; ++q)
                    if (tD[q] == kl) eqb += ((uint32_t)tPos[q] < mypos);
            }
            uint32_t tr = a0 + less + eqb;
            S += (long long)prArr[mypos] * (long long)tr;
        }
    }

    // ---- reduce + epilogue (identical math to R1/R2 verified kernels) ----
#pragma unroll
    for (int off = 32; off > 0; off >>= 1)
        S += __shfl_down(S, off, 64);
    if (lane == 0) atomicAdd(sumAcc, (unsigned long long)S);
    __syncthreads();

    if (tid == 0) {
        double Sd = (double)(long long)(*sumAcc);
        double mean = (double)(KSEL - 1) * 0.5;
        double cov = Sd / (double)KSEL - mean * mean;
        double stdprod = (double)KSEL * (double)(KSEL + 1) / 12.0;
        out[c] = (float)(cov / (stdprod + 1e-8));
    }
}

extern "C" void kernel_launch(void* const* d_in, const int* in_sizes, int n_in,
                              void* d_out, int out_size, void* d_ws, size_t ws_size,
                              hipStream_t stream) {
    const float* preds   = (const float*)d_in[0];
    const float* targets = (const float*)d_in[1];
    float* out = (float*)d_out;
    hipLaunchKernelGGL(rank_ic_kernel, dim3(NCOLS), dim3(THREADS), 0, stream,
                       preds, targets, out);
}

// Round 4
// 691.376 us; speedup vs baseline: 2.1934x; 1.1909x over previous
//
#include <hip/hip_runtime.h>
#include <stdint.h>

// preds/targets: (8192, 64, 64) f32. N=8192 rows, C=4096 cols, k=N/2.
#define NROWS   8192
#define NCOLS   4096
#define KSEL    4096
#define THREADS 1024
#define NSUBP   2560   // p sub-bins: 256 + 8192/4 = 2304 <= 2560 (= 640*4)
#define NSUBT   1536   // t sub-bins: 256 + 4096/4 = 1280 <= 1536 (= 384*4)
#define TGT     4

// ---- LDS layout (64,616 B) ----
// pD    @0      u32[8196] (8192 + 4 pad = 0xFFFFFFFF sentinels)
// pIdx  @32784  u16[8192]
// cnt   @49168  u32[2560]
// histW @59408  u32[4*256]
// combo @63504  u32[256]
// wtot  @64528  u32[16], wtot2 @64592 u32[4], sumAcc @64608 u64
// t-phase aliases (into pD region, written only after p-rank barrier):
// tD @0 u32[4100] (pad @4096..4099) | tPos @16400 u16[4096] | prArr @24592 u16[4096]

__device__ __forceinline__ uint32_t orderable(uint32_t b) {
    return b ^ ((b & 0x80000000u) ? 0xFFFFFFFFu : 0x80000000u);
}

__device__ __forceinline__ uint32_t wave_incl_scan(uint32_t v, int lane) {
#pragma unroll
    for (int off = 1; off < 64; off <<= 1) {
        uint32_t n = __shfl_up(v, off, 64);
        if (lane >= off) v += n;
    }
    return v;
}

// histW (4 private copies, 256 bins) -> combo[b] = (subBase<<16)|nsplit
__device__ __forceinline__ void alloc_subbins(uint32_t* histW, uint32_t* combo,
                                              uint32_t* wtot2, int tid, int lane, int wave) {
    uint32_t myNs = 0, myIncl = 0;
    if (tid < 256) {
        uint32_t n = histW[tid] + histW[256 + tid] + histW[512 + tid] + histW[768 + tid];
        myNs = (n + TGT - 1) / TGT;
        myIncl = wave_incl_scan(myNs, lane);
        if (lane == 63) wtot2[wave] = myIncl;
    }
    __syncthreads();
    if (tid < 4) {
        uint32_t orig = wtot2[tid], v = orig;
        uint32_t n1 = __shfl_up(v, 1, 64); if (tid >= 1) v += n1;
        uint32_t n2 = __shfl_up(v, 2, 64); if (tid >= 2) v += n2;
        wtot2[tid] = v - orig;   // exclusive
    }
    __syncthreads();
    if (tid < 256) combo[tid] = ((wtot2[wave] + myIncl - myNs) << 16) | myNs;
    __syncthreads();
}

// exclusive scan of cnt[0..4*n4) in place; after this cnt[s] = start of bin s
__device__ __forceinline__ void scan_cnt(uint32_t* cnt, uint32_t* wtot,
                                         int tid, int lane, int wave, int n4) {
    uint4 c4 = make_uint4(0, 0, 0, 0);
    bool act = tid < n4;
    if (act) c4 = ((uint4*)cnt)[tid];
    uint32_t s4 = c4.x + c4.y + c4.z + c4.w;
    uint32_t incl = wave_incl_scan(s4, lane);
    if (lane == 63) wtot[wave] = incl;
    __syncthreads();
    if (tid < 16) {
        uint32_t orig = wtot[tid], v = orig;
#pragma unroll
        for (int off = 1; off < 16; off <<= 1) {
            uint32_t n = __shfl_up(v, off, 64);
            if (tid >= off) v += n;
        }
        wtot[tid] = v - orig;
    }
    __syncthreads();
    if (act) {
        uint32_t base = wtot[wave] + incl - s4;
        uint4 o; o.x = base; o.y = base + c4.x; o.z = o.y + c4.y; o.w = o.z + c4.z;
        ((uint4*)cnt)[tid] = o;
    }
    __syncthreads();
}

__device__ __forceinline__ uint32_t bin_of(uint32_t key, const uint32_t* combo) {
    uint32_t cb = combo[key >> 24];
    return (cb >> 16) + ((((key >> 16) & 255u) * (cb & 0xFFFFu)) >> 8);
}

__global__ __launch_bounds__(THREADS, 8)
void rank_ic_kernel(const float* __restrict__ preds,
                    const float* __restrict__ targets,
                    float* __restrict__ out) {
    const int bid = blockIdx.x;
    const int c = ((bid & 7) << 9) | (bid >> 3);  // XCD swizzle
    const int tid = threadIdx.x;
    const int lane = tid & 63;
    const int wave = tid >> 6;
    const int hg = wave >> 2;

    __shared__ __align__(16) uint8_t smem[64616];
    uint32_t* pD     = (uint32_t*)smem;
    uint16_t* pIdx   = (uint16_t*)(smem + 32784);
    uint32_t* cnt    = (uint32_t*)(smem + 49168);
    uint32_t* histW  = (uint32_t*)(smem + 59408);
    uint32_t* combo  = (uint32_t*)(smem + 63504);
    uint32_t* wtot   = (uint32_t*)(smem + 64528);
    uint32_t* wtot2  = (uint32_t*)(smem + 64592);
    unsigned long long* sumAcc = (unsigned long long*)(smem + 64608);
    uint32_t* tD     = (uint32_t*)smem;              // aliases pD (post p-rank)
    uint16_t* tPos   = (uint16_t*)(smem + 16400);
    uint16_t* prArr  = (uint16_t*)(smem + 24592);

    // ---- p: load column, build keys (ascending d == descending p) ----
    uint32_t d[8];
#pragma unroll
    for (int j = 0; j < 8; ++j)
        d[j] = ~orderable(__float_as_uint(preds[(size_t)(j * THREADS + tid) * NCOLS + c]));

    // ---- init zero (b128) + sentinels ----
    const uint4 z4 = make_uint4(0, 0, 0, 0);
    if (tid < NSUBP / 4) ((uint4*)cnt)[tid] = z4;
    if (tid < 256) ((uint4*)histW)[tid] = z4;
    if (tid < 4) pD[NROWS + tid] = 0xFFFFFFFFu;   // span-overrun pad (> any finite key)
    if (tid == 0) *sumAcc = 0ull;
    __syncthreads();

    // ---- p: privatized top-8 histogram ----
#pragma unroll
    for (int j = 0; j < 8; ++j) atomicAdd(&histW[hg * 256 + (d[j] >> 24)], 1u);
    __syncthreads();

    alloc_subbins(histW, combo, wtot2, tid, lane, wave);

    // ---- p: count pass; atomic return value IS the within-bin sequence ----
    uint32_t pk[8];
#pragma unroll
    for (int j = 0; j < 8; ++j) {
        uint32_t s = bin_of(d[j], combo);
        uint32_t sq = atomicAdd(&cnt[s], 1u);
        pk[j] = s | (sq << 16);                  // s < 4096 fits 12 bits
    }
    __syncthreads();

    scan_cnt(cnt, wtot, tid, lane, wave, NSUBP / 4);  // cnt[s] = bin start

    // ---- p: atomic-free scatter ----
#pragma unroll
    for (int j = 0; j < 8; ++j) {
        uint32_t s = pk[j] & 0xFFFu;
        uint32_t dst = cnt[s] + (pk[j] >> 16);
        pD[dst]   = d[j];
        pIdx[dst] = (uint16_t)(j * THREADS + tid);
    }
    __syncthreads();

    // ---- p: shared-span rank scan (positions tid*8 .. tid*8+7) ----
    uint32_t k8[8], idx8[8], rp[8];  // rp: low16 = rank, high16 = p_r
    {
        uint4 ka = ((const uint4*)pD)[tid * 2];
        uint4 kb = ((const uint4*)pD)[tid * 2 + 1];
        k8[0]=ka.x; k8[1]=ka.y; k8[2]=ka.z; k8[3]=ka.w;
        k8[4]=kb.x; k8[5]=kb.y; k8[6]=kb.z; k8[7]=kb.w;
        uint4 ib = ((const uint4*)pIdx)[tid];
        idx8[0]=ib.x&0xFFFFu; idx8[1]=ib.x>>16; idx8[2]=ib.y&0xFFFFu; idx8[3]=ib.y>>16;
        idx8[4]=ib.z&0xFFFFu; idx8[5]=ib.z>>16; idx8[6]=ib.w&0xFFFFu; idx8[7]=ib.w>>16;
    }
    {
        uint32_t A = cnt[bin_of(k8[0], combo)];
        uint32_t B = cnt[bin_of(k8[7], combo) + 1];
        uint32_t a0 = A & ~3u;
        uint32_t less[8] = {0,0,0,0,0,0,0,0}, eqc[8] = {0,0,0,0,0,0,0,0};
        for (uint32_t q = a0; q < B; q += 4) {
            uint4 kv = ((const uint4*)pD)[q >> 2];
#pragma unroll
            for (int j = 0; j < 8; ++j) {
                uint32_t kl = k8[j];
                less[j] += (kv.x < kl) + (kv.y < kl) + (kv.z < kl) + (kv.w < kl);
                eqc[j]  += (kv.x == kl) + (kv.y == kl) + (kv.z == kl) + (kv.w == kl);
            }
        }
#pragma unroll
        for (int j = 0; j < 8; ++j) {
            uint32_t i = a0 + less[j];           // first member of tie group (global)
            uint32_t eqb = 0;
            if (eqc[j] > 1) {                    // rare: true f32 ties
                for (uint32_t q = A; q < B; ++q)
                    if (pD[q] == k8[j]) eqb += ((uint32_t)pIdx[q] < idx8[j]);
            }
            uint32_t r = i + eqb;
            int jj = (int)(i + eqc[j] - 1); if (jj > KSEL - 1) jj = KSEL - 1;
            int pr = (KSEL - 1) - (int)i - jj + (int)r;  // verified tie rule (R1-R3)
            rp[j] = r | ((uint32_t)pr << 16);
        }
    }
    __syncthreads();  // pD/pIdx/cnt reads done; region reusable

    // ---- t prep: zero, pad, prArr, direct global gather of selected t ----
    if (tid < NSUBT / 4) ((uint4*)cnt)[tid] = z4;
    if (tid < 256) ((uint4*)histW)[tid] = z4;
    if (tid < 4) tD[KSEL + tid] = 0xFFFFFFFFu;
    uint32_t tk[8] = {0,0,0,0,0,0,0,0};
#pragma unroll
    for (int j = 0; j < 8; ++j) {
        uint32_t r = rp[j] & 0xFFFFu;
        if (r < KSEL) {
            prArr[r] = (uint16_t)(rp[j] >> 16);
            tk[j] = orderable(__float_as_uint(targets[(size_t)idx8[j] * NCOLS + c]));
        }
    }
    __syncthreads();

    // ---- t: histogram (selected only) ----
#pragma unroll
    for (int j = 0; j < 8; ++j)
        if ((rp[j] & 0xFFFFu) < KSEL) atomicAdd(&histW[hg * 256 + (tk[j] >> 24)], 1u);
    __syncthreads();

    alloc_subbins(histW, combo, wtot2, tid, lane, wave);

    uint32_t tpk[8];
#pragma unroll
    for (int j = 0; j < 8; ++j)
        if ((rp[j] & 0xFFFFu) < KSEL) {
            uint32_t s = bin_of(tk[j], combo);
            uint32_t sq = atomicAdd(&cnt[s], 1u);
            tpk[j] = s | (sq << 16);
        }
    __syncthreads();

    scan_cnt(cnt, wtot, tid, lane, wave, NSUBT / 4);

#pragma unroll
    for (int j = 0; j < 8; ++j) {
        uint32_t r = rp[j] & 0xFFFFu;
        if (r < KSEL) {
            uint32_t s = tpk[j] & 0xFFFu;
            uint32_t dst = cnt[s] + (tpk[j] >> 16);
            tD[dst]   = tk[j];
            tPos[dst] = (uint16_t)r;             // tie-break by p-position
        }
    }
    __syncthreads();

    // ---- t: shared-span rank scan + dot (positions tid*4 .. tid*4+3) ----
    long long S = 0;
    {
        uint4 kv4 = ((const uint4*)tD)[tid];
        uint2 pp  = ((const uint2*)tPos)[tid];
        uint32_t kk[4] = {kv4.x, kv4.y, kv4.z, kv4.w};
        uint32_t pq[4] = {pp.x & 0xFFFFu, pp.x >> 16, pp.y & 0xFFFFu, pp.y >> 16};
        uint32_t A = cnt[bin_of(kk[0], combo)];
        uint32_t B = cnt[bin_of(kk[3], combo) + 1];
        uint32_t a0 = A & ~3u;
        uint32_t less[4] = {0,0,0,0}, eqc[4] = {0,0,0,0};
        for (uint32_t q = a0; q < B; q += 4) {
            uint4 kv = ((const uint4*)tD)[q >> 2];
#pragma unroll
            for (int m = 0; m < 4; ++m) {
                uint32_t kl = kk[m];
                less[m] += (kv.x < kl) + (kv.y < kl) + (kv.z < kl) + (kv.w < kl);
                eqc[m]  += (kv.x == kl) + (kv.y == kl) + (kv.z == kl) + (kv.w == kl);
            }
        }
#pragma unroll
        for (int m = 0; m < 4; ++m) {
            uint32_t eqb = 0;
            if (eqc[m] > 1) {
                for (uint32_t q = A; q < B; ++q)
                    if (tD[q] == kk[m]) eqb += ((uint32_t)tPos[q] < pq[m]);
            }
            uint32_t tr = a0 + less[m] + eqb;
            S += (long long)prArr[pq[m]] * (long long)tr;
        }
    }

    // ---- reduce + epilogue (identical math to R1-R3 verified kernels) ----
#pragma unroll
    for (int off = 32; off > 0; off >>= 1)
        S += __shfl_down(S, off, 64);
    if (lane == 0) atomicAdd(sumAcc, (unsigned long long)S);
    __syncthreads();

    if (tid == 0) {
        double Sd = (double)(long long)(*sumAcc);
        double mean = (double)(KSEL - 1) * 0.5;
        double cov = Sd / (double)KSEL - mean * mean;
        double stdprod = (double)KSEL * (double)(KSEL + 1) / 12.0;
        out[c] = (float)(cov / (stdprod + 1e-8));
    }
}

extern "C" void kernel_launch(void* const* d_in, const int* in_sizes, int n_in,
                              void* d_out, int out_size, void* d_ws, size_t ws_size,
                              hipStream_t stream) {
    const float* preds   = (const float*)d_in[0];
    const float* targets = (const float*)d_in[1];
    float* out = (float*)d_out;
    hipLaunchKernelGGL(rank_ic_kernel, dim3(NCOLS), dim3(THREADS), 0, stream,
                       preds, targets, out);
}